// Round 1
// baseline (790.552 us; speedup 1.0000x reference)
//
#include <hip/hip_runtime.h>
#include <cstdint>
#include <cstddef>

// Problem dims
#define NB 2
#define NTT 2048
#define ND 1024
#define NK 8
#define NF 4096
#define NTOK (NB*NTT)        // 4096 tokens
#define LAMBDA_C 0.5f

// Output layout (float units)
#define Y_SZ   (NTOK*ND)         // 4194304
#define LG_OFF Y_SZ              // logits
#define SC_OFF (LG_OFF + NTOK*NK) // sel_counts (8)
#define AD_OFF (SC_OFF + NK)      // avg_density (1)

// Workspace layout (4-byte units)
#define WS_SEG    0        // seg_start[9] (ints)
#define WS_NTILES 12       // int
#define WS_TILEK  32       // int[1024]
#define WS_TILER  1056     // int[1024]
#define WS_PTOK   4096     // int[32768]
#define WS_PCOEF  36864    // float[32768]
#define WS_COEF   69632    // float[NTOK*NK] = 32768
#define WS_H      102400   // bf16 h buffer starts here (bytes offset = 409600, 16B aligned)

#define TM 64
#define TN 64
#define KC 16

__device__ __forceinline__ float bf2f(unsigned short u){
    return __uint_as_float(((unsigned int)u) << 16);
}
__device__ __forceinline__ unsigned short f2bf(float f){
    unsigned int u = __float_as_uint(f);
    return (unsigned short)((u + 0x7fffu + ((u >> 16) & 1u)) >> 16);
}
__device__ __forceinline__ float gelu_exact(float v){
    return 0.5f * v * (1.0f + erff(v * 0.70710678118654752440f));
}

// ---------------- gating: logits, softmax, mask, coefficients, sel_counts ----------------
__global__ __launch_bounds__(256) void k_gating(
    const float* __restrict__ x, const float* __restrict__ pl,
    const float* __restrict__ Wt, const float* __restrict__ Wgt,
    const float* __restrict__ Wel, float* __restrict__ out,
    float* __restrict__ coef)
{
    int t = blockIdx.x;
    const float* xt = x + (size_t)t * ND;
    float acc[NK] = {0,0,0,0,0,0,0,0};
    for (int d = threadIdx.x; d < ND; d += 256){
        float xv = xt[d];
        const float4* w = (const float4*)(Wt + (size_t)d * NK);
        float4 w0 = w[0], w1 = w[1];
        acc[0] += xv*w0.x; acc[1] += xv*w0.y; acc[2] += xv*w0.z; acc[3] += xv*w0.w;
        acc[4] += xv*w1.x; acc[5] += xv*w1.y; acc[6] += xv*w1.z; acc[7] += xv*w1.w;
    }
    __shared__ float red[4][NK];
    #pragma unroll
    for (int k = 0; k < NK; k++){
        float v = acc[k];
        #pragma unroll
        for (int off = 32; off; off >>= 1) v += __shfl_down(v, off);
        if ((threadIdx.x & 63) == 0) red[threadIdx.x >> 6][k] = v;
    }
    __syncthreads();
    if (threadIdx.x == 0){
        const float* p = pl + (size_t)t * NK;
        float pv[NK];
        #pragma unroll
        for (int j = 0; j < NK; j++) pv[j] = p[j];
        float lg[NK]; float mx = -1e30f;
        #pragma unroll
        for (int k = 0; k < NK; k++){
            float v = red[0][k] + red[1][k] + red[2][k] + red[3][k];
            #pragma unroll
            for (int j = 0; j < NK; j++) v += pv[j] * Wgt[j*NK + k];
            lg[k] = v; mx = fmaxf(mx, v);
            out[LG_OFF + (size_t)t*NK + k] = v;
        }
        float e[NK]; float s = 0.f;
        #pragma unroll
        for (int k = 0; k < NK; k++){ e[k] = expf(lg[k] - mx); s += e[k]; }
        float g[NK]; float gsum = 0.f;
        #pragma unroll
        for (int k = 0; k < NK; k++){
            float st = e[k] / s;
            float we = 1.f / (1.f + expf(-Wel[k]));
            bool m = st > LAMBDA_C * we;
            g[k] = m ? st : 0.f;
            gsum += g[k];
        }
        float inv = 1.f / (gsum + 1e-6f);
        #pragma unroll
        for (int k = 0; k < NK; k++){
            coef[(size_t)t*NK + k] = g[k] * inv;
            if (g[k] > 0.f) atomicAdd(&out[SC_OFF + k], 1.0f);
        }
    }
}

// ---------------- scan: compact (expert,token) pairs ordered by (k,t); build tile list ----------------
__global__ __launch_bounds__(256) void k_scan(
    const float* __restrict__ coef, int* __restrict__ wsi,
    float* __restrict__ wsf, float* __restrict__ out, int pair_cap)
{
    __shared__ int wsum[4];
    __shared__ int sbase;
    int tid = threadIdx.x, lane = tid & 63, w = tid >> 6;
    if (tid == 0) sbase = 0;
    __syncthreads();
    int* seg   = wsi + WS_SEG;
    int* ptok  = wsi + WS_PTOK;
    float* pcoef = wsf + WS_PCOEF;
    for (int k = 0; k < NK; k++){
        if (tid == 0) seg[k] = sbase;
        __syncthreads();
        for (int c0 = 0; c0 < NTOK; c0 += 256){
            int t = c0 + tid;
            float c = coef[(size_t)t*NK + k];
            bool m = c > 0.f;
            unsigned long long bal = __ballot(m);
            int pre = __popcll(bal & ((1ull << lane) - 1ull));
            if (lane == 0) wsum[w] = __popcll(bal);
            __syncthreads();
            int base = sbase;
            for (int j = 0; j < w; j++) base += wsum[j];
            if (m){
                int pos = base + pre;
                if (pos < pair_cap){ ptok[pos] = t; pcoef[pos] = c; }
            }
            __syncthreads();
            if (tid == 0) sbase += wsum[0] + wsum[1] + wsum[2] + wsum[3];
            __syncthreads();
        }
    }
    if (tid == 0){
        seg[NK] = sbase;
        out[AD_OFF] = (float)sbase / (float)NTOK;
        int nt = 0;
        int* tk = wsi + WS_TILEK;
        int* tr = wsi + WS_TILER;
        for (int k = 0; k < NK; k++){
            for (int r = seg[k]; r < seg[k+1]; r += TM){
                tk[nt] = k; tr[nt] = r; nt++;
            }
        }
        wsi[WS_NTILES] = nt;
    }
}

// ---------------- GEMM1: h = gelu(gather(x) @ W1[k] + b1[k]), h stored bf16 ----------------
__global__ __launch_bounds__(256) void k_gemm1(
    const float* __restrict__ x, const float* __restrict__ W1,
    const float* __restrict__ b1, const int* __restrict__ wsi,
    unsigned short* __restrict__ hbuf, int pair_cap)
{
    __shared__ float As[TM][20];
    __shared__ float Bs[KC][68];
    __shared__ int stok[TM];
    const int* seg  = wsi + WS_SEG;
    const int* tk   = wsi + WS_TILEK;
    const int* tr   = wsi + WS_TILER;
    const int* ptok = wsi + WS_PTOK;
    int ntm = wsi[WS_NTILES];
    int nwork = ntm * (NF / TN);
    int tid = threadIdx.x;
    int ty = tid >> 4, tx = tid & 15;
    for (int widx = blockIdx.x; widx < nwork; widx += gridDim.x){
        int mt = widx % ntm;
        int ft = widx / ntm;
        int k = tk[mt];
        int row0 = tr[mt];
        if (row0 >= pair_cap) { continue; }
        int nrows = min(TM, seg[k+1] - row0);
        int f0 = ft * TN;
        if (tid < TM){
            int r = row0 + tid;
            stok[tid] = (tid < nrows && r < pair_cap) ? ptok[r] : ptok[row0];
        }
        float acc[4][4] = {};
        __syncthreads();
        for (int d0 = 0; d0 < ND; d0 += KC){
            {
                int r = tid >> 2, c4 = (tid & 3) * 4;
                float4 v = *(const float4*)(x + (size_t)stok[r]*ND + d0 + c4);
                As[r][c4+0] = v.x; As[r][c4+1] = v.y; As[r][c4+2] = v.z; As[r][c4+3] = v.w;
            }
            {
                int dd = tid >> 4, c4 = (tid & 15) * 4;
                float4 v = *(const float4*)(W1 + ((size_t)k*ND + d0 + dd)*NF + f0 + c4);
                Bs[dd][c4+0] = v.x; Bs[dd][c4+1] = v.y; Bs[dd][c4+2] = v.z; Bs[dd][c4+3] = v.w;
            }
            __syncthreads();
            #pragma unroll
            for (int dd = 0; dd < KC; dd++){
                float a0 = As[ty*4+0][dd], a1 = As[ty*4+1][dd];
                float a2 = As[ty*4+2][dd], a3 = As[ty*4+3][dd];
                float b0 = Bs[dd][tx*4+0], b1v = Bs[dd][tx*4+1];
                float b2v = Bs[dd][tx*4+2], b3 = Bs[dd][tx*4+3];
                acc[0][0] += a0*b0; acc[0][1] += a0*b1v; acc[0][2] += a0*b2v; acc[0][3] += a0*b3;
                acc[1][0] += a1*b0; acc[1][1] += a1*b1v; acc[1][2] += a1*b2v; acc[1][3] += a1*b3;
                acc[2][0] += a2*b0; acc[2][1] += a2*b1v; acc[2][2] += a2*b2v; acc[2][3] += a2*b3;
                acc[3][0] += a3*b0; acc[3][1] += a3*b1v; acc[3][2] += a3*b2v; acc[3][3] += a3*b3;
            }
            __syncthreads();
        }
        #pragma unroll
        for (int i = 0; i < 4; i++){
            int r = ty*4 + i;
            if (r < nrows && (row0 + r) < pair_cap){
                size_t hrow = (size_t)(row0 + r) * NF;
                #pragma unroll
                for (int j = 0; j < 4; j++){
                    int f = f0 + tx*4 + j;
                    float v = acc[i][j] + b1[(size_t)k*NF + f];
                    hbuf[hrow + f] = f2bf(gelu_exact(v));
                }
            }
        }
        __syncthreads();
    }
}

// ---------------- GEMM2: y[tok] += coef * (h @ W2[k] + b2[k]) ----------------
__global__ __launch_bounds__(256) void k_gemm2(
    const unsigned short* __restrict__ hbuf, const float* __restrict__ W2,
    const float* __restrict__ b2, const int* __restrict__ wsi,
    const float* __restrict__ wsf, float* __restrict__ out, int pair_cap)
{
    __shared__ float As[TM][20];
    __shared__ float Bs[KC][68];
    __shared__ int stok[TM];
    __shared__ float scoef[TM];
    const int* seg  = wsi + WS_SEG;
    const int* tk   = wsi + WS_TILEK;
    const int* tr   = wsi + WS_TILER;
    const int* ptok = wsi + WS_PTOK;
    const float* pcoef = wsf + WS_PCOEF;
    int ntm = wsi[WS_NTILES];
    int nwork = ntm * (ND / TN);
    int tid = threadIdx.x;
    int ty = tid >> 4, tx = tid & 15;
    for (int widx = blockIdx.x; widx < nwork; widx += gridDim.x){
        int mt = widx % ntm;
        int dt = widx / ntm;
        int k = tk[mt];
        int row0 = tr[mt];
        if (row0 >= pair_cap) { continue; }
        int nrows = min(TM, seg[k+1] - row0);
        int d0q = dt * TN;
        if (tid < TM){
            int r = row0 + tid;
            bool v = (tid < nrows && r < pair_cap);
            stok[tid]  = v ? ptok[r] : 0;
            scoef[tid] = v ? pcoef[r] : 0.f;
        }
        float acc[4][4] = {};
        __syncthreads();
        for (int f0 = 0; f0 < NF; f0 += KC){
            {
                int r = tid >> 2, c4 = (tid & 3) * 4;
                int rr = row0 + r; if (rr >= pair_cap) rr = pair_cap - 1;
                ushort4 v = *(const ushort4*)(hbuf + (size_t)rr*NF + f0 + c4);
                As[r][c4+0] = bf2f(v.x); As[r][c4+1] = bf2f(v.y);
                As[r][c4+2] = bf2f(v.z); As[r][c4+3] = bf2f(v.w);
            }
            {
                int dd = tid >> 4, c4 = (tid & 15) * 4;
                float4 v = *(const float4*)(W2 + ((size_t)k*NF + f0 + dd)*ND + d0q + c4);
                Bs[dd][c4+0] = v.x; Bs[dd][c4+1] = v.y; Bs[dd][c4+2] = v.z; Bs[dd][c4+3] = v.w;
            }
            __syncthreads();
            #pragma unroll
            for (int dd = 0; dd < KC; dd++){
                float a0 = As[ty*4+0][dd], a1 = As[ty*4+1][dd];
                float a2 = As[ty*4+2][dd], a3 = As[ty*4+3][dd];
                float b0 = Bs[dd][tx*4+0], b1v = Bs[dd][tx*4+1];
                float b2v = Bs[dd][tx*4+2], b3 = Bs[dd][tx*4+3];
                acc[0][0] += a0*b0; acc[0][1] += a0*b1v; acc[0][2] += a0*b2v; acc[0][3] += a0*b3;
                acc[1][0] += a1*b0; acc[1][1] += a1*b1v; acc[1][2] += a1*b2v; acc[1][3] += a1*b3;
                acc[2][0] += a2*b0; acc[2][1] += a2*b1v; acc[2][2] += a2*b2v; acc[2][3] += a2*b3;
                acc[3][0] += a3*b0; acc[3][1] += a3*b1v; acc[3][2] += a3*b2v; acc[3][3] += a3*b3;
            }
            __syncthreads();
        }
        #pragma unroll
        for (int i = 0; i < 4; i++){
            int r = ty*4 + i;
            if (r < nrows && (row0 + r) < pair_cap){
                float c = scoef[r];
                int tokr = stok[r];
                #pragma unroll
                for (int j = 0; j < 4; j++){
                    int d = d0q + tx*4 + j;
                    float v = (acc[i][j] + b2[(size_t)k*ND + d]) * c;
                    atomicAdd(&out[(size_t)tokr*ND + d], v);
                }
            }
        }
        __syncthreads();
    }
}

extern "C" void kernel_launch(void* const* d_in, const int* in_sizes, int n_in,
                              void* d_out, int out_size, void* d_ws, size_t ws_size,
                              hipStream_t stream)
{
    const float* x   = (const float*)d_in[0];
    const float* pl  = (const float*)d_in[1];
    const float* Wt  = (const float*)d_in[2];
    const float* Wgt = (const float*)d_in[3];
    const float* Wel = (const float*)d_in[4];
    const float* W1  = (const float*)d_in[5];
    const float* b1  = (const float*)d_in[6];
    const float* W2  = (const float*)d_in[7];
    const float* b2  = (const float*)d_in[8];
    float* out = (float*)d_out;
    int* wsi   = (int*)d_ws;
    float* wsf = (float*)d_ws;
    unsigned short* hbuf = (unsigned short*)((char*)d_ws + (size_t)WS_H*4);

    long long avail = (long long)ws_size - (long long)WS_H*4;
    long long cap = avail / ((long long)NF*2);
    if (cap > (long long)NTOK*NK) cap = (long long)NTOK*NK;
    int pair_cap = (int)cap;

    hipMemsetAsync(d_out, 0, (size_t)out_size*sizeof(float), stream);
    k_gating<<<NTOK, 256, 0, stream>>>(x, pl, Wt, Wgt, Wel, out, wsf + WS_COEF);
    k_scan<<<1, 256, 0, stream>>>(wsf + WS_COEF, wsi, wsf, out, pair_cap);
    if (pair_cap >= TM){
        k_gemm1<<<4096, 256, 0, stream>>>(x, W1, b1, wsi, hbuf, pair_cap);
        k_gemm2<<<2048, 256, 0, stream>>>(hbuf, W2, b2, wsi, wsf, out, pair_cap);
    }
}

// Round 3
// 353.004 us; speedup vs baseline: 2.2395x; 2.2395x over previous
//
#include <hip/hip_runtime.h>
#include <cstdint>
#include <cstddef>

// Problem dims
#define NB 2
#define NTT 2048
#define ND 1024
#define NK 8
#define NF 4096
#define NTOK (NB*NTT)        // 4096 tokens
#define LAMBDA_C 0.5f

// Output layout (float units)
#define Y_SZ   (NTOK*ND)
#define LG_OFF Y_SZ
#define SC_OFF (LG_OFF + NTOK*NK)
#define AD_OFF (SC_OFF + NK)

// Workspace layout (4-byte units)
#define WS_CNT    0        // int[8]  (zeroed each call)
#define WS_SEG    8        // int[9]
#define WS_NTILES 17       // int
#define WS_TILEK  32       // int[1024]
#define WS_TILER  1056     // int[1024]
#define WS_PTOK   4096     // int[32768]
#define WS_PCOEF  36864    // float[32768]
#define WS_COEF   69632    // float[NTOK*NK]
#define WS_H      102400   // f16 h buffer (byte offset 409600)

#define BM 64
#define BN 128
#define BK 64
#define SPLITK2 4

typedef float  f32x4 __attribute__((ext_vector_type(4)));
typedef _Float16 f16x8 __attribute__((ext_vector_type(8)));
typedef unsigned int u32x2 __attribute__((ext_vector_type(2)));
typedef unsigned int u32x4 __attribute__((ext_vector_type(4)));

__device__ __forceinline__ unsigned int pkrtz(float a, float b){
    auto h = __builtin_amdgcn_cvt_pkrtz(a, b);
    return __builtin_bit_cast(unsigned int, h);
}
__device__ __forceinline__ float gelu_exact(float v){
    return 0.5f * v * (1.0f + erff(v * 0.70710678118654752440f));
}

// ---------------- gating ----------------
__global__ __launch_bounds__(256) void k_gating(
    const float* __restrict__ x, const float* __restrict__ pl,
    const float* __restrict__ Wt, const float* __restrict__ Wgt,
    const float* __restrict__ Wel, float* __restrict__ out,
    float* __restrict__ coef, int* __restrict__ cnt)
{
    int t = blockIdx.x;
    const float* xt = x + (size_t)t * ND;
    float acc[NK] = {0,0,0,0,0,0,0,0};
    for (int d = threadIdx.x; d < ND; d += 256){
        float xv = xt[d];
        const float4* w = (const float4*)(Wt + (size_t)d * NK);
        float4 w0 = w[0], w1 = w[1];
        acc[0] += xv*w0.x; acc[1] += xv*w0.y; acc[2] += xv*w0.z; acc[3] += xv*w0.w;
        acc[4] += xv*w1.x; acc[5] += xv*w1.y; acc[6] += xv*w1.z; acc[7] += xv*w1.w;
    }
    __shared__ float red[4][NK];
    #pragma unroll
    for (int k = 0; k < NK; k++){
        float v = acc[k];
        #pragma unroll
        for (int off = 32; off; off >>= 1) v += __shfl_down(v, off);
        if ((threadIdx.x & 63) == 0) red[threadIdx.x >> 6][k] = v;
    }
    __syncthreads();
    if (threadIdx.x == 0){
        const float* p = pl + (size_t)t * NK;
        float pv[NK];
        #pragma unroll
        for (int j = 0; j < NK; j++) pv[j] = p[j];
        float lg[NK]; float mx = -1e30f;
        #pragma unroll
        for (int k = 0; k < NK; k++){
            float v = red[0][k] + red[1][k] + red[2][k] + red[3][k];
            #pragma unroll
            for (int j = 0; j < NK; j++) v += pv[j] * Wgt[j*NK + k];
            lg[k] = v; mx = fmaxf(mx, v);
            out[LG_OFF + (size_t)t*NK + k] = v;
        }
        float e[NK]; float s = 0.f;
        #pragma unroll
        for (int k = 0; k < NK; k++){ e[k] = expf(lg[k] - mx); s += e[k]; }
        float g[NK]; float gsum = 0.f;
        #pragma unroll
        for (int k = 0; k < NK; k++){
            float st = e[k] / s;
            float we = 1.f / (1.f + expf(-Wel[k]));
            bool m = st > LAMBDA_C * we;
            g[k] = m ? st : 0.f;
            gsum += g[k];
        }
        float inv = 1.f / (gsum + 1e-6f);
        #pragma unroll
        for (int k = 0; k < NK; k++){
            coef[(size_t)t*NK + k] = g[k] * inv;
            if (g[k] > 0.f) atomicAdd(&cnt[k], 1);
        }
    }
}

// ---------------- scan: per-expert compaction (8 blocks) ----------------
__global__ __launch_bounds__(256) void k_scan(
    const float* __restrict__ coef, int* __restrict__ wsi,
    float* __restrict__ wsf, int pair_cap)
{
    int k = blockIdx.x;
    const int* cnt = wsi + WS_CNT;
    int base = 0;
    for (int j = 0; j < k; j++) base += cnt[j];
    int tid = threadIdx.x, lane = tid & 63, w = tid >> 6;
    __shared__ int wsum[4];
    __shared__ int sbase;
    if (tid == 0){
        sbase = base;
        wsi[WS_SEG + k] = base;
        if (k == NK-1) wsi[WS_SEG + NK] = base + cnt[k];
    }
    __syncthreads();
    int* ptok = wsi + WS_PTOK;
    float* pc = wsf + WS_PCOEF;
    for (int c0 = 0; c0 < NTOK; c0 += 256){
        int t = c0 + tid;
        float c = coef[(size_t)t*NK + k];
        bool m = c > 0.f;
        unsigned long long bal = __ballot(m);
        int pre = __popcll(bal & ((1ull << lane) - 1ull));
        if (lane == 0) wsum[w] = __popcll(bal);
        __syncthreads();
        int b = sbase;
        for (int j = 0; j < w; j++) b += wsum[j];
        if (m){
            int pos = b + pre;
            if (pos < pair_cap){ ptok[pos] = t; pc[pos] = c; }
        }
        __syncthreads();
        if (tid == 0) sbase += wsum[0] + wsum[1] + wsum[2] + wsum[3];
        __syncthreads();
    }
}

// ---------------- tiles + small outputs ----------------
__global__ void k_tiles(int* __restrict__ wsi, float* __restrict__ out, int pair_cap)
{
    if (threadIdx.x == 0 && blockIdx.x == 0){
        const int* cnt = wsi + WS_CNT;
        const int* seg = wsi + WS_SEG;
        int total = 0;
        for (int k = 0; k < NK; k++){ total += cnt[k]; out[SC_OFF + k] = (float)cnt[k]; }
        out[AD_OFF] = (float)total / (float)NTOK;
        int nt = 0;
        for (int k = 0; k < NK; k++){
            int e = min(seg[k+1], pair_cap);
            for (int r = seg[k]; r < e; r += BM){
                wsi[WS_TILEK + nt] = k; wsi[WS_TILER + nt] = r; nt++;
            }
        }
        wsi[WS_NTILES] = nt;
    }
}

// ---------------- GEMM1 (MFMA f16): h = gelu(gather(x) @ W1[k] + b1[k]) ----------------
__global__ __launch_bounds__(256, 2) void k_gemm1(
    const float* __restrict__ x, const float* __restrict__ W1,
    const float* __restrict__ b1, const int* __restrict__ wsi,
    unsigned short* __restrict__ hbuf, int pair_cap)
{
    __shared__ char lds[24576];          // A: 64x128B @0, B: 128x128B @8192
    __shared__ int stok[BM];
    const int* seg  = wsi + WS_SEG;
    const int* tk   = wsi + WS_TILEK;
    const int* tr   = wsi + WS_TILER;
    const int* ptok = wsi + WS_PTOK;
    int ntm = wsi[WS_NTILES];
    int nwork = ntm * (NF / BN);
    int tid  = threadIdx.x;
    int lane = tid & 63;
    int w    = tid >> 6;
    int wr = w >> 1, wc = w & 1;
    int l15 = lane & 15, q = lane >> 4;
    unsigned swzL = (unsigned)((lane & 7) << 4);
    unsigned qk16 = (unsigned)(q << 4);
    unsigned abase = (unsigned)(wr*32 + l15) * 128u;
    unsigned bbase = 8192u + (unsigned)(wc*64 + l15) * 128u;
    int arow = tid >> 2, akseg = tid & 3;
    unsigned awz   = (unsigned)((arow & 7) << 4);
    unsigned adst0 = (unsigned)arow*128u + (((unsigned)(akseg*32)) ^ awz);
    unsigned adst1 = (unsigned)arow*128u + (((unsigned)(akseg*32 + 16)) ^ awz);
    int bk4 = tid & 7, bf4 = tid >> 3;
    unsigned bro = 8192u + (unsigned)(bf4*4) * 128u;

    for (int widx = blockIdx.x; widx < nwork; widx += gridDim.x){
        int mt = widx % ntm;
        int ft = widx / ntm;
        int kexp = tk[mt];
        int row0 = tr[mt];
        int nrows = min(BM, seg[kexp+1] - row0);
        int f0 = ft * BN;
        __syncthreads();
        if (tid < BM) stok[tid] = (tid < nrows) ? ptok[row0 + tid] : ptok[row0];
        __syncthreads();
        const float* xrow = x + (size_t)stok[arow]*ND + akseg*16;
        const float* bp   = W1 + (size_t)kexp*ND*NF + f0 + bf4*4;
        f32x4 la[4]; f32x4 lb[8];
        #pragma unroll
        for (int i = 0; i < 4; i++) la[i] = *(const f32x4*)(xrow + i*4);
        #pragma unroll
        for (int i = 0; i < 2; i++)
            #pragma unroll
            for (int r = 0; r < 4; r++)
                lb[i*4+r] = *(const f32x4*)(bp + (size_t)((bk4 + i*8)*4 + r)*NF);
        f32x4 acc[2][4] = {};
        for (int t = 0; t < ND/BK; t++){
            if (t) __syncthreads();
            { // stage A
                unsigned u[8];
                #pragma unroll
                for (int j = 0; j < 8; j++)
                    u[j] = pkrtz(la[j>>1][(j&1)*2], la[j>>1][(j&1)*2+1]);
                *(u32x4*)(&lds[adst0]) = (u32x4){u[0],u[1],u[2],u[3]};
                *(u32x4*)(&lds[adst1]) = (u32x4){u[4],u[5],u[6],u[7]};
            }
            // stage B with in-register 4x4 transpose
            #pragma unroll
            for (int i = 0; i < 2; i++){
                unsigned wA[4], wB[4];
                #pragma unroll
                for (int r = 0; r < 4; r++){
                    wA[r] = pkrtz(lb[i*4+r][0], lb[i*4+r][1]);
                    wB[r] = pkrtz(lb[i*4+r][2], lb[i*4+r][3]);
                }
                unsigned kq8 = (unsigned)((bk4 + i*8) * 8);
                #pragma unroll
                for (int j = 0; j < 4; j++){
                    unsigned s0 = (j < 2) ? wA[1] : wB[1];
                    unsigned s1 = (j < 2) ? wA[0] : wB[0];
                    unsigned s2 = (j < 2) ? wA[3] : wB[3];
                    unsigned s3 = (j < 2) ? wA[2] : wB[2];
                    unsigned sel = (j & 1) ? 0x07060302u : 0x05040100u;
                    unsigned o0 = __builtin_amdgcn_perm(s0, s1, sel);
                    unsigned o1 = __builtin_amdgcn_perm(s2, s3, sel);
                    unsigned fswz = (unsigned)(((bf4*4 + j) & 7) << 4);
                    *(u32x2*)(&lds[bro + (unsigned)j*128u + (kq8 ^ fswz)]) = (u32x2){o0, o1};
                }
            }
            __syncthreads();
            if (t + 1 < ND/BK){ // prefetch next tile into regs (overlaps MFMA)
                const float* xn = xrow + (t+1)*BK;
                #pragma unroll
                for (int i = 0; i < 4; i++) la[i] = *(const f32x4*)(xn + i*4);
                const float* bn = bp + (size_t)(t+1)*BK*NF;
                #pragma unroll
                for (int i = 0; i < 2; i++)
                    #pragma unroll
                    for (int r = 0; r < 4; r++)
                        lb[i*4+r] = *(const f32x4*)(bn + (size_t)((bk4 + i*8)*4 + r)*NF);
            }
            #pragma unroll
            for (int kk = 0; kk < 2; kk++){
                unsigned sb = ((unsigned)(kk*64) + qk16) ^ swzL;
                f16x8 a0 = *(const f16x8*)(&lds[abase + sb]);
                f16x8 a1 = *(const f16x8*)(&lds[abase + 2048u + sb]);
                #pragma unroll
                for (int n = 0; n < 4; n++){
                    f16x8 bf_ = *(const f16x8*)(&lds[bbase + (unsigned)n*2048u + sb]);
                    acc[0][n] = __builtin_amdgcn_mfma_f32_16x16x32_f16(a0, bf_, acc[0][n], 0, 0, 0);
                    acc[1][n] = __builtin_amdgcn_mfma_f32_16x16x32_f16(a1, bf_, acc[1][n], 0, 0, 0);
                }
            }
        }
        const float* b1k = b1 + (size_t)kexp*NF;
        #pragma unroll
        for (int n = 0; n < 4; n++){
            int f = f0 + wc*64 + n*16 + l15;
            float bv = b1k[f];
            #pragma unroll
            for (int m = 0; m < 2; m++){
                int rl = wr*32 + m*16 + q*4;
                #pragma unroll
                for (int i = 0; i < 4; i++){
                    int r = rl + i;
                    if (r < nrows && row0 + r < pair_cap){
                        float v = gelu_exact(acc[m][n][i] + bv);
                        hbuf[(size_t)(row0+r)*NF + f] = (unsigned short)(pkrtz(v, 0.f) & 0xffffu);
                    }
                }
            }
        }
    }
}

// ---------------- GEMM2 (MFMA f16, split-K): y += coef*(h @ W2[k] + b2[k]) ----------------
__global__ __launch_bounds__(256, 2) void k_gemm2(
    const unsigned short* __restrict__ hbuf, const float* __restrict__ W2,
    const float* __restrict__ b2, const int* __restrict__ wsi,
    const float* __restrict__ wsf, float* __restrict__ out, int pair_cap)
{
    __shared__ char lds[24576];
    __shared__ int stok[BM];
    __shared__ float scoef[BM];
    const int* seg  = wsi + WS_SEG;
    const int* tk   = wsi + WS_TILEK;
    const int* tr   = wsi + WS_TILER;
    const int* ptok = wsi + WS_PTOK;
    const float* pcoef = wsf + WS_PCOEF;
    int ntm = wsi[WS_NTILES];
    int nwork = ntm * (ND / BN) * SPLITK2;
    int tid  = threadIdx.x;
    int lane = tid & 63;
    int w    = tid >> 6;
    int wr = w >> 1, wc = w & 1;
    int l15 = lane & 15, q = lane >> 4;
    unsigned swzL = (unsigned)((lane & 7) << 4);
    unsigned qk16 = (unsigned)(q << 4);
    unsigned abase = (unsigned)(wr*32 + l15) * 128u;
    unsigned bbase = 8192u + (unsigned)(wc*64 + l15) * 128u;
    int arow = tid >> 2, akseg = tid & 3;
    unsigned awz   = (unsigned)((arow & 7) << 4);
    unsigned adst0 = (unsigned)arow*128u + (((unsigned)(akseg*32)) ^ awz);
    unsigned adst1 = (unsigned)arow*128u + (((unsigned)(akseg*32 + 16)) ^ awz);
    int bk4 = tid & 7, bf4 = tid >> 3;
    unsigned bro = 8192u + (unsigned)(bf4*4) * 128u;
    const int KT = (NF / SPLITK2) / BK;   // 16 k-tiles per split

    for (int widx = blockIdx.x; widx < nwork; widx += gridDim.x){
        int mt = widx % ntm;
        int rest = widx / ntm;
        int dt = rest & 7;
        int sp = rest >> 3;
        int kexp = tk[mt];
        int row0 = tr[mt];
        int nrows = min(BM, seg[kexp+1] - row0);
        int d0 = dt * BN;
        __syncthreads();
        if (tid < BM){
            int r = row0 + tid;
            bool v = (tid < nrows && r < pair_cap);
            stok[tid]  = v ? ptok[r] : 0;
            scoef[tid] = v ? pcoef[r] : 0.f;
        }
        __syncthreads();
        const unsigned short* hrow = hbuf + (size_t)min(row0 + arow, pair_cap-1)*NF + sp*(NF/SPLITK2) + akseg*16;
        const float* bp = W2 + (size_t)kexp*NF*ND + (size_t)sp*(NF/SPLITK2)*ND + d0 + bf4*4;
        u32x4 ha[2]; f32x4 lb[8];
        ha[0] = *(const u32x4*)(hrow);
        ha[1] = *(const u32x4*)(hrow + 8);
        #pragma unroll
        for (int i = 0; i < 2; i++)
            #pragma unroll
            for (int r = 0; r < 4; r++)
                lb[i*4+r] = *(const f32x4*)(bp + (size_t)((bk4 + i*8)*4 + r)*ND);
        f32x4 acc[2][4] = {};
        for (int t = 0; t < KT; t++){
            if (t) __syncthreads();
            *(u32x4*)(&lds[adst0]) = ha[0];
            *(u32x4*)(&lds[adst1]) = ha[1];
            #pragma unroll
            for (int i = 0; i < 2; i++){
                unsigned wA[4], wB[4];
                #pragma unroll
                for (int r = 0; r < 4; r++){
                    wA[r] = pkrtz(lb[i*4+r][0], lb[i*4+r][1]);
                    wB[r] = pkrtz(lb[i*4+r][2], lb[i*4+r][3]);
                }
                unsigned kq8 = (unsigned)((bk4 + i*8) * 8);
                #pragma unroll
                for (int j = 0; j < 4; j++){
                    unsigned s0 = (j < 2) ? wA[1] : wB[1];
                    unsigned s1 = (j < 2) ? wA[0] : wB[0];
                    unsigned s2 = (j < 2) ? wA[3] : wB[3];
                    unsigned s3 = (j < 2) ? wA[2] : wB[2];
                    unsigned sel = (j & 1) ? 0x07060302u : 0x05040100u;
                    unsigned o0 = __builtin_amdgcn_perm(s0, s1, sel);
                    unsigned o1 = __builtin_amdgcn_perm(s2, s3, sel);
                    unsigned fswz = (unsigned)(((bf4*4 + j) & 7) << 4);
                    *(u32x2*)(&lds[bro + (unsigned)j*128u + (kq8 ^ fswz)]) = (u32x2){o0, o1};
                }
            }
            __syncthreads();
            if (t + 1 < KT){
                const unsigned short* hn = hrow + (t+1)*BK;
                ha[0] = *(const u32x4*)(hn);
                ha[1] = *(const u32x4*)(hn + 8);
                const float* bn = bp + (size_t)(t+1)*BK*ND;
                #pragma unroll
                for (int i = 0; i < 2; i++)
                    #pragma unroll
                    for (int r = 0; r < 4; r++)
                        lb[i*4+r] = *(const f32x4*)(bn + (size_t)((bk4 + i*8)*4 + r)*ND);
            }
            #pragma unroll
            for (int kk = 0; kk < 2; kk++){
                unsigned sb = ((unsigned)(kk*64) + qk16) ^ swzL;
                f16x8 a0 = *(const f16x8*)(&lds[abase + sb]);
                f16x8 a1 = *(const f16x8*)(&lds[abase + 2048u + sb]);
                #pragma unroll
                for (int n = 0; n < 4; n++){
                    f16x8 bf_ = *(const f16x8*)(&lds[bbase + (unsigned)n*2048u + sb]);
                    acc[0][n] = __builtin_amdgcn_mfma_f32_16x16x32_f16(a0, bf_, acc[0][n], 0, 0, 0);
                    acc[1][n] = __builtin_amdgcn_mfma_f32_16x16x32_f16(a1, bf_, acc[1][n], 0, 0, 0);
                }
            }
        }
        const float* b2k = b2 + (size_t)kexp*ND;
        #pragma unroll
        for (int n = 0; n < 4; n++){
            int d = d0 + wc*64 + n*16 + l15;
            float bv = (sp == 0) ? b2k[d] : 0.f;
            #pragma unroll
            for (int m = 0; m < 2; m++){
                int rl = wr*32 + m*16 + q*4;
                #pragma unroll
                for (int i = 0; i < 4; i++){
                    int r = rl + i;
                    if (r < nrows && row0 + r < pair_cap){
                        float c = scoef[r];
                        atomicAdd(&out[(size_t)stok[r]*ND + d], c * (acc[m][n][i] + bv));
                    }
                }
            }
        }
    }
}

extern "C" void kernel_launch(void* const* d_in, const int* in_sizes, int n_in,
                              void* d_out, int out_size, void* d_ws, size_t ws_size,
                              hipStream_t stream)
{
    const float* x   = (const float*)d_in[0];
    const float* pl  = (const float*)d_in[1];
    const float* Wt  = (const float*)d_in[2];
    const float* Wgt = (const float*)d_in[3];
    const float* Wel = (const float*)d_in[4];
    const float* W1  = (const float*)d_in[5];
    const float* b1  = (const float*)d_in[6];
    const float* W2  = (const float*)d_in[7];
    const float* b2  = (const float*)d_in[8];
    float* out = (float*)d_out;
    int* wsi   = (int*)d_ws;
    float* wsf = (float*)d_ws;
    unsigned short* hbuf = (unsigned short*)((char*)d_ws + (size_t)WS_H*4);

    long long avail = (long long)ws_size - (long long)WS_H*4;
    long long cap = avail / ((long long)NF*2);
    if (cap > (long long)NTOK*NK) cap = (long long)NTOK*NK;
    int pair_cap = (int)cap;

    hipMemsetAsync(d_out, 0, (size_t)out_size*sizeof(float), stream);
    hipMemsetAsync(d_ws, 0, 32, stream);   // cnt[8]
    k_gating<<<NTOK, 256, 0, stream>>>(x, pl, Wt, Wgt, Wel, out, wsf + WS_COEF, wsi + WS_CNT);
    if (pair_cap > 0){
        k_scan<<<NK, 256, 0, stream>>>(wsf + WS_COEF, wsi, wsf, pair_cap);
        k_tiles<<<1, 64, 0, stream>>>(wsi, out, pair_cap);
        k_gemm1<<<2048, 256, 0, stream>>>(x, W1, b1, wsi, hbuf, pair_cap);
        k_gemm2<<<2048, 256, 0, stream>>>(hbuf, W2, b2, wsi, wsf, out, pair_cap);
    }
}

// Round 4
// 308.244 us; speedup vs baseline: 2.5647x; 1.1452x over previous
//
#include <hip/hip_runtime.h>
#include <cstdint>
#include <cstddef>

// Problem dims
#define NB 2
#define NTT 2048
#define ND 1024
#define NK 8
#define NF 4096
#define NTOK (NB*NTT)        // 4096 tokens
#define LAMBDA_C 0.5f

// Output layout (float units)
#define Y_SZ   (NTOK*ND)
#define LG_OFF Y_SZ
#define SC_OFF (LG_OFF + NTOK*NK)
#define AD_OFF (SC_OFF + NK)

// Workspace layout (4-byte units)
#define WS_CNT    0        // int[8]  (zeroed each call)
#define WS_SEG    8        // int[9]
#define WS_NTILES 17       // int
#define WS_TILEK  32       // int[1024]
#define WS_TILER  1056     // int[1024]
#define WS_PTOK   4096     // int[32768]
#define WS_PCOEF  36864    // float[32768]
#define WS_COEF   69632    // float[NTOK*NK]
#define WS_H      102400   // f16 h buffer (byte offset 409600)

#define BM 64
#define BN 128
#define BK 64
#define SPLITK2 4

typedef float  f32x4 __attribute__((ext_vector_type(4)));
typedef _Float16 f16x8 __attribute__((ext_vector_type(8)));
typedef unsigned int u32x2 __attribute__((ext_vector_type(2)));
typedef unsigned int u32x4 __attribute__((ext_vector_type(4)));

__device__ __forceinline__ unsigned int pkrtz(float a, float b){
    auto h = __builtin_amdgcn_cvt_pkrtz(a, b);
    return __builtin_bit_cast(unsigned int, h);
}
__device__ __forceinline__ float gelu_exact(float v){
    return 0.5f * v * (1.0f + erff(v * 0.70710678118654752440f));
}

// ---------------- gating ----------------
__global__ __launch_bounds__(256) void k_gating(
    const float* __restrict__ x, const float* __restrict__ pl,
    const float* __restrict__ Wt, const float* __restrict__ Wgt,
    const float* __restrict__ Wel, float* __restrict__ out,
    float* __restrict__ coef, int* __restrict__ cnt)
{
    int t = blockIdx.x;
    const float* xt = x + (size_t)t * ND;
    float acc[NK] = {0,0,0,0,0,0,0,0};
    for (int d = threadIdx.x; d < ND; d += 256){
        float xv = xt[d];
        const float4* w = (const float4*)(Wt + (size_t)d * NK);
        float4 w0 = w[0], w1 = w[1];
        acc[0] += xv*w0.x; acc[1] += xv*w0.y; acc[2] += xv*w0.z; acc[3] += xv*w0.w;
        acc[4] += xv*w1.x; acc[5] += xv*w1.y; acc[6] += xv*w1.z; acc[7] += xv*w1.w;
    }
    __shared__ float red[4][NK];
    #pragma unroll
    for (int k = 0; k < NK; k++){
        float v = acc[k];
        #pragma unroll
        for (int off = 32; off; off >>= 1) v += __shfl_down(v, off);
        if ((threadIdx.x & 63) == 0) red[threadIdx.x >> 6][k] = v;
    }
    __syncthreads();
    if (threadIdx.x == 0){
        const float* p = pl + (size_t)t * NK;
        float pv[NK];
        #pragma unroll
        for (int j = 0; j < NK; j++) pv[j] = p[j];
        float lg[NK]; float mx = -1e30f;
        #pragma unroll
        for (int k = 0; k < NK; k++){
            float v = red[0][k] + red[1][k] + red[2][k] + red[3][k];
            #pragma unroll
            for (int j = 0; j < NK; j++) v += pv[j] * Wgt[j*NK + k];
            lg[k] = v; mx = fmaxf(mx, v);
            out[LG_OFF + (size_t)t*NK + k] = v;
        }
        float e[NK]; float s = 0.f;
        #pragma unroll
        for (int k = 0; k < NK; k++){ e[k] = expf(lg[k] - mx); s += e[k]; }
        float g[NK]; float gsum = 0.f;
        #pragma unroll
        for (int k = 0; k < NK; k++){
            float st = e[k] / s;
            float we = 1.f / (1.f + expf(-Wel[k]));
            bool m = st > LAMBDA_C * we;
            g[k] = m ? st : 0.f;
            gsum += g[k];
        }
        float inv = 1.f / (gsum + 1e-6f);
        #pragma unroll
        for (int k = 0; k < NK; k++){
            coef[(size_t)t*NK + k] = g[k] * inv;
            if (g[k] > 0.f) atomicAdd(&cnt[k], 1);
        }
    }
}

// ---------------- scan: per-expert compaction (8 blocks) ----------------
__global__ __launch_bounds__(256) void k_scan(
    const float* __restrict__ coef, int* __restrict__ wsi,
    float* __restrict__ wsf, int pair_cap)
{
    int k = blockIdx.x;
    const int* cnt = wsi + WS_CNT;
    int base = 0;
    for (int j = 0; j < k; j++) base += cnt[j];
    int tid = threadIdx.x, lane = tid & 63, w = tid >> 6;
    __shared__ int wsum[4];
    __shared__ int sbase;
    if (tid == 0){
        sbase = base;
        wsi[WS_SEG + k] = base;
        if (k == NK-1) wsi[WS_SEG + NK] = base + cnt[k];
    }
    __syncthreads();
    int* ptok = wsi + WS_PTOK;
    float* pc = wsf + WS_PCOEF;
    for (int c0 = 0; c0 < NTOK; c0 += 256){
        int t = c0 + tid;
        float c = coef[(size_t)t*NK + k];
        bool m = c > 0.f;
        unsigned long long bal = __ballot(m);
        int pre = __popcll(bal & ((1ull << lane) - 1ull));
        if (lane == 0) wsum[w] = __popcll(bal);
        __syncthreads();
        int b = sbase;
        for (int j = 0; j < w; j++) b += wsum[j];
        if (m){
            int pos = b + pre;
            if (pos < pair_cap){ ptok[pos] = t; pc[pos] = c; }
        }
        __syncthreads();
        if (tid == 0) sbase += wsum[0] + wsum[1] + wsum[2] + wsum[3];
        __syncthreads();
    }
}

// ---------------- tiles + small outputs ----------------
__global__ void k_tiles(int* __restrict__ wsi, float* __restrict__ out, int pair_cap)
{
    if (threadIdx.x == 0 && blockIdx.x == 0){
        const int* cnt = wsi + WS_CNT;
        const int* seg = wsi + WS_SEG;
        int total = 0;
        for (int k = 0; k < NK; k++){ total += cnt[k]; out[SC_OFF + k] = (float)cnt[k]; }
        out[AD_OFF] = (float)total / (float)NTOK;
        int nt = 0;
        for (int k = 0; k < NK; k++){
            int e = min(seg[k+1], pair_cap);
            for (int r = seg[k]; r < e; r += BM){
                wsi[WS_TILEK + nt] = k; wsi[WS_TILER + nt] = r; nt++;
            }
        }
        wsi[WS_NTILES] = nt;
    }
}

// XCD-chunked bijective work partition: blockIdx%8 -> XCD; each XCD owns a
// contiguous item range so same-B-slab m-tiles (adjacent items) share one L2.
#define XCD_PART_LOOP(nwork)                                              \
    int q_ = (nwork) >> 3, r_ = (nwork) & 7;                              \
    int xcd_ = blockIdx.x & 7;                                            \
    int slot_ = blockIdx.x >> 3;                                          \
    int nslot_ = gridDim.x >> 3;                                          \
    int cntw_ = q_ + (xcd_ < r_ ? 1 : 0);                                 \
    int start_ = xcd_ * q_ + (xcd_ < r_ ? xcd_ : r_);                     \
    for (int p_ = slot_; p_ < cntw_; p_ += nslot_)

// ---------------- GEMM1 (MFMA f16): h = gelu(gather(x) @ W1[k] + b1[k]) ----------------
__global__ __launch_bounds__(256, 2) void k_gemm1(
    const float* __restrict__ x, const float* __restrict__ W1,
    const float* __restrict__ b1, const int* __restrict__ wsi,
    unsigned short* __restrict__ hbuf, int pair_cap)
{
    __shared__ char lds[24576];          // A: 64x128B @0, B: 128x128B @8192
    __shared__ int stok[BM];
    const int* seg  = wsi + WS_SEG;
    const int* tk   = wsi + WS_TILEK;
    const int* tr   = wsi + WS_TILER;
    const int* ptok = wsi + WS_PTOK;
    int ntm = wsi[WS_NTILES];
    int nwork = ntm * (NF / BN);
    int tid  = threadIdx.x;
    int lane = tid & 63;
    int w    = tid >> 6;
    int wr = w >> 1, wc = w & 1;
    int l15 = lane & 15, q = lane >> 4;
    unsigned swzL = (unsigned)((lane & 7) << 4);
    unsigned qk16 = (unsigned)(q << 4);
    unsigned abase = (unsigned)(wr*32 + l15) * 128u;
    unsigned bbase = 8192u + (unsigned)(wc*64 + l15) * 128u;
    int arow = tid >> 2, akseg = tid & 3;
    unsigned awz   = (unsigned)((arow & 7) << 4);
    unsigned adst0 = (unsigned)arow*128u + (((unsigned)(akseg*32)) ^ awz);
    unsigned adst1 = (unsigned)arow*128u + (((unsigned)(akseg*32 + 16)) ^ awz);
    int bk4 = tid & 7, bf4 = tid >> 3;
    unsigned bro = 8192u + (unsigned)(bf4*4) * 128u;

    XCD_PART_LOOP(nwork){
        int widx = start_ + p_;
        int mt = widx % ntm;
        int ft = widx / ntm;
        int kexp = tk[mt];
        int row0 = tr[mt];
        int nrows = min(BM, seg[kexp+1] - row0);
        int f0 = ft * BN;
        __syncthreads();
        if (tid < BM) stok[tid] = (tid < nrows) ? ptok[row0 + tid] : ptok[row0];
        __syncthreads();
        const float* xrow = x + (size_t)stok[arow]*ND + akseg*16;
        const float* bp   = W1 + (size_t)kexp*ND*NF + f0 + bf4*4;
        f32x4 la[4]; f32x4 lb[8];
        #pragma unroll
        for (int i = 0; i < 4; i++) la[i] = *(const f32x4*)(xrow + i*4);
        #pragma unroll
        for (int i = 0; i < 2; i++)
            #pragma unroll
            for (int r = 0; r < 4; r++)
                lb[i*4+r] = *(const f32x4*)(bp + (size_t)((bk4 + i*8)*4 + r)*NF);
        f32x4 acc[2][4] = {};
        for (int t = 0; t < ND/BK; t++){
            if (t) __syncthreads();
            { // stage A
                unsigned u[8];
                #pragma unroll
                for (int j = 0; j < 8; j++)
                    u[j] = pkrtz(la[j>>1][(j&1)*2], la[j>>1][(j&1)*2+1]);
                *(u32x4*)(&lds[adst0]) = (u32x4){u[0],u[1],u[2],u[3]};
                *(u32x4*)(&lds[adst1]) = (u32x4){u[4],u[5],u[6],u[7]};
            }
            // stage B with in-register 4x4 transpose
            #pragma unroll
            for (int i = 0; i < 2; i++){
                unsigned wA[4], wB[4];
                #pragma unroll
                for (int r = 0; r < 4; r++){
                    wA[r] = pkrtz(lb[i*4+r][0], lb[i*4+r][1]);
                    wB[r] = pkrtz(lb[i*4+r][2], lb[i*4+r][3]);
                }
                unsigned kq8 = (unsigned)((bk4 + i*8) * 8);
                #pragma unroll
                for (int j = 0; j < 4; j++){
                    unsigned s0 = (j < 2) ? wA[1] : wB[1];
                    unsigned s1 = (j < 2) ? wA[0] : wB[0];
                    unsigned s2 = (j < 2) ? wA[3] : wB[3];
                    unsigned s3 = (j < 2) ? wA[2] : wB[2];
                    unsigned sel = (j & 1) ? 0x07060302u : 0x05040100u;
                    unsigned o0 = __builtin_amdgcn_perm(s0, s1, sel);
                    unsigned o1 = __builtin_amdgcn_perm(s2, s3, sel);
                    unsigned fswz = (unsigned)(((bf4*4 + j) & 7) << 4);
                    *(u32x2*)(&lds[bro + (unsigned)j*128u + (kq8 ^ fswz)]) = (u32x2){o0, o1};
                }
            }
            __syncthreads();
            if (t + 1 < ND/BK){ // prefetch next tile into regs (overlaps MFMA)
                const float* xn = xrow + (t+1)*BK;
                #pragma unroll
                for (int i = 0; i < 4; i++) la[i] = *(const f32x4*)(xn + i*4);
                const float* bn = bp + (size_t)(t+1)*BK*NF;
                #pragma unroll
                for (int i = 0; i < 2; i++)
                    #pragma unroll
                    for (int r = 0; r < 4; r++)
                        lb[i*4+r] = *(const f32x4*)(bn + (size_t)((bk4 + i*8)*4 + r)*NF);
            }
            #pragma unroll
            for (int kk = 0; kk < 2; kk++){
                unsigned sb = ((unsigned)(kk*64) + qk16) ^ swzL;
                f16x8 a0 = *(const f16x8*)(&lds[abase + sb]);
                f16x8 a1 = *(const f16x8*)(&lds[abase + 2048u + sb]);
                #pragma unroll
                for (int n = 0; n < 4; n++){
                    f16x8 bf_ = *(const f16x8*)(&lds[bbase + (unsigned)n*2048u + sb]);
                    acc[0][n] = __builtin_amdgcn_mfma_f32_16x16x32_f16(a0, bf_, acc[0][n], 0, 0, 0);
                    acc[1][n] = __builtin_amdgcn_mfma_f32_16x16x32_f16(a1, bf_, acc[1][n], 0, 0, 0);
                }
            }
        }
        const float* b1k = b1 + (size_t)kexp*NF;
        #pragma unroll
        for (int n = 0; n < 4; n++){
            int f = f0 + wc*64 + n*16 + l15;
            float bv = b1k[f];
            #pragma unroll
            for (int m = 0; m < 2; m++){
                int rl = wr*32 + m*16 + q*4;
                #pragma unroll
                for (int i = 0; i < 4; i++){
                    int r = rl + i;
                    if (r < nrows && row0 + r < pair_cap){
                        float v = gelu_exact(acc[m][n][i] + bv);
                        hbuf[(size_t)(row0+r)*NF + f] = (unsigned short)(pkrtz(v, 0.f) & 0xffffu);
                    }
                }
            }
        }
    }
}

// ---------------- GEMM2 (MFMA f16, split-K): y += coef*(h @ W2[k] + b2[k]) ----------------
__global__ __launch_bounds__(256, 2) void k_gemm2(
    const unsigned short* __restrict__ hbuf, const float* __restrict__ W2,
    const float* __restrict__ b2, const int* __restrict__ wsi,
    const float* __restrict__ wsf, float* __restrict__ out, int pair_cap)
{
    __shared__ char lds[24576];
    __shared__ int stok[BM];
    __shared__ float scoef[BM];
    const int* seg  = wsi + WS_SEG;
    const int* tk   = wsi + WS_TILEK;
    const int* tr   = wsi + WS_TILER;
    const int* ptok = wsi + WS_PTOK;
    const float* pcoef = wsf + WS_PCOEF;
    int ntm = wsi[WS_NTILES];
    int nwork = ntm * (ND / BN) * SPLITK2;
    int tid  = threadIdx.x;
    int lane = tid & 63;
    int w    = tid >> 6;
    int wr = w >> 1, wc = w & 1;
    int l15 = lane & 15, q = lane >> 4;
    unsigned swzL = (unsigned)((lane & 7) << 4);
    unsigned qk16 = (unsigned)(q << 4);
    unsigned abase = (unsigned)(wr*32 + l15) * 128u;
    unsigned bbase = 8192u + (unsigned)(wc*64 + l15) * 128u;
    int arow = tid >> 2, akseg = tid & 3;
    unsigned awz   = (unsigned)((arow & 7) << 4);
    unsigned adst0 = (unsigned)arow*128u + (((unsigned)(akseg*32)) ^ awz);
    unsigned adst1 = (unsigned)arow*128u + (((unsigned)(akseg*32 + 16)) ^ awz);
    int bk4 = tid & 7, bf4 = tid >> 3;
    unsigned bro = 8192u + (unsigned)(bf4*4) * 128u;
    const int KT = (NF / SPLITK2) / BK;   // 16 k-tiles per split

    XCD_PART_LOOP(nwork){
        int widx = start_ + p_;
        int mt = widx % ntm;
        int rest = widx / ntm;
        int dt = rest & 7;
        int sp = rest >> 3;
        int kexp = tk[mt];
        int row0 = tr[mt];
        int nrows = min(BM, seg[kexp+1] - row0);
        int d0 = dt * BN;
        __syncthreads();
        if (tid < BM){
            int r = row0 + tid;
            bool v = (tid < nrows && r < pair_cap);
            stok[tid]  = v ? ptok[r] : 0;
            scoef[tid] = v ? pcoef[r] : 0.f;
        }
        __syncthreads();
        const unsigned short* hrow = hbuf + (size_t)min(row0 + arow, pair_cap-1)*NF + sp*(NF/SPLITK2) + akseg*16;
        const float* bp = W2 + (size_t)kexp*NF*ND + (size_t)sp*(NF/SPLITK2)*ND + d0 + bf4*4;
        u32x4 ha[2]; f32x4 lb[8];
        ha[0] = *(const u32x4*)(hrow);
        ha[1] = *(const u32x4*)(hrow + 8);
        #pragma unroll
        for (int i = 0; i < 2; i++)
            #pragma unroll
            for (int r = 0; r < 4; r++)
                lb[i*4+r] = *(const f32x4*)(bp + (size_t)((bk4 + i*8)*4 + r)*ND);
        f32x4 acc[2][4] = {};
        for (int t = 0; t < KT; t++){
            if (t) __syncthreads();
            *(u32x4*)(&lds[adst0]) = ha[0];
            *(u32x4*)(&lds[adst1]) = ha[1];
            #pragma unroll
            for (int i = 0; i < 2; i++){
                unsigned wA[4], wB[4];
                #pragma unroll
                for (int r = 0; r < 4; r++){
                    wA[r] = pkrtz(lb[i*4+r][0], lb[i*4+r][1]);
                    wB[r] = pkrtz(lb[i*4+r][2], lb[i*4+r][3]);
                }
                unsigned kq8 = (unsigned)((bk4 + i*8) * 8);
                #pragma unroll
                for (int j = 0; j < 4; j++){
                    unsigned s0 = (j < 2) ? wA[1] : wB[1];
                    unsigned s1 = (j < 2) ? wA[0] : wB[0];
                    unsigned s2 = (j < 2) ? wA[3] : wB[3];
                    unsigned s3 = (j < 2) ? wA[2] : wB[2];
                    unsigned sel = (j & 1) ? 0x07060302u : 0x05040100u;
                    unsigned o0 = __builtin_amdgcn_perm(s0, s1, sel);
                    unsigned o1 = __builtin_amdgcn_perm(s2, s3, sel);
                    unsigned fswz = (unsigned)(((bf4*4 + j) & 7) << 4);
                    *(u32x2*)(&lds[bro + (unsigned)j*128u + (kq8 ^ fswz)]) = (u32x2){o0, o1};
                }
            }
            __syncthreads();
            if (t + 1 < KT){
                const unsigned short* hn = hrow + (t+1)*BK;
                ha[0] = *(const u32x4*)(hn);
                ha[1] = *(const u32x4*)(hn + 8);
                const float* bn = bp + (size_t)(t+1)*BK*ND;
                #pragma unroll
                for (int i = 0; i < 2; i++)
                    #pragma unroll
                    for (int r = 0; r < 4; r++)
                        lb[i*4+r] = *(const f32x4*)(bn + (size_t)((bk4 + i*8)*4 + r)*ND);
            }
            #pragma unroll
            for (int kk = 0; kk < 2; kk++){
                unsigned sb = ((unsigned)(kk*64) + qk16) ^ swzL;
                f16x8 a0 = *(const f16x8*)(&lds[abase + sb]);
                f16x8 a1 = *(const f16x8*)(&lds[abase + 2048u + sb]);
                #pragma unroll
                for (int n = 0; n < 4; n++){
                    f16x8 bf_ = *(const f16x8*)(&lds[bbase + (unsigned)n*2048u + sb]);
                    acc[0][n] = __builtin_amdgcn_mfma_f32_16x16x32_f16(a0, bf_, acc[0][n], 0, 0, 0);
                    acc[1][n] = __builtin_amdgcn_mfma_f32_16x16x32_f16(a1, bf_, acc[1][n], 0, 0, 0);
                }
            }
        }
        const float* b2k = b2 + (size_t)kexp*ND;
        #pragma unroll
        for (int n = 0; n < 4; n++){
            int d = d0 + wc*64 + n*16 + l15;
            float bv = (sp == 0) ? b2k[d] : 0.f;
            #pragma unroll
            for (int m = 0; m < 2; m++){
                int rl = wr*32 + m*16 + q*4;
                #pragma unroll
                for (int i = 0; i < 4; i++){
                    int r = rl + i;
                    if (r < nrows && row0 + r < pair_cap){
                        float c = scoef[r];
                        atomicAdd(&out[(size_t)stok[r]*ND + d], c * (acc[m][n][i] + bv));
                    }
                }
            }
        }
    }
}

extern "C" void kernel_launch(void* const* d_in, const int* in_sizes, int n_in,
                              void* d_out, int out_size, void* d_ws, size_t ws_size,
                              hipStream_t stream)
{
    const float* x   = (const float*)d_in[0];
    const float* pl  = (const float*)d_in[1];
    const float* Wt  = (const float*)d_in[2];
    const float* Wgt = (const float*)d_in[3];
    const float* Wel = (const float*)d_in[4];
    const float* W1  = (const float*)d_in[5];
    const float* b1  = (const float*)d_in[6];
    const float* W2  = (const float*)d_in[7];
    const float* b2  = (const float*)d_in[8];
    float* out = (float*)d_out;
    int* wsi   = (int*)d_ws;
    float* wsf = (float*)d_ws;
    unsigned short* hbuf = (unsigned short*)((char*)d_ws + (size_t)WS_H*4);

    long long avail = (long long)ws_size - (long long)WS_H*4;
    long long cap = avail / ((long long)NF*2);
    if (cap > (long long)NTOK*NK) cap = (long long)NTOK*NK;
    int pair_cap = (int)cap;

    hipMemsetAsync(d_out, 0, (size_t)out_size*sizeof(float), stream);
    hipMemsetAsync(d_ws, 0, 32, stream);   // cnt[8]
    k_gating<<<NTOK, 256, 0, stream>>>(x, pl, Wt, Wgt, Wel, out, wsf + WS_COEF, wsi + WS_CNT);
    if (pair_cap > 0){
        k_scan<<<NK, 256, 0, stream>>>(wsf + WS_COEF, wsi, wsf, pair_cap);
        k_tiles<<<1, 64, 0, stream>>>(wsi, out, pair_cap);
        k_gemm1<<<2048, 256, 0, stream>>>(x, W1, b1, wsi, hbuf, pair_cap);
        k_gemm2<<<2048, 256, 0, stream>>>(hbuf, W2, b2, wsi, wsf, out, pair_cap);
    }
}